// Round 5
// baseline (682.181 us; speedup 1.0000x reference)
//
#include <hip/hip_runtime.h>
#include <hip/hip_bf16.h>
#include <stdint.h>

#define HH   1024
#define FF   1024
#define NE   32
#define NK   4
#define CAP  256
#define MT   32          // A-tile rows per block (full-K staging)

typedef __bf16 bf16x8 __attribute__((ext_vector_type(8)));
typedef __bf16 bf16x4 __attribute__((ext_vector_type(4)));
typedef __bf16 bf16x2 __attribute__((ext_vector_type(2)));
typedef float  f32x4v __attribute__((ext_vector_type(4)));

// ---------------- workspace layout (bytes) ----------------
#define OFF_TOK 1024        // 32*256*4 = 32 KiB
#define OFF_WGT 33792       // 32 KiB
#define OFF_ES  66560       // 16 KiB (packed e<<16|pos per token,k)
#define OFF_RW  82944       // 16 KiB (routing weight per token,k)
#define OFF_T   131072      // 2 MiB  bf16 t
#define OFF_H   2228224     // 16 MiB bf16 h (mlp1 out)
#define OFF_H2  19005440    // 16 MiB bf16 h2 (mlp2 out)

// zero cnt + FULL tok/wgt tables so slots >= Me read token 0 with weight 0
// -> mlp kernels are branch-free over all 256 slots.
__global__ __launch_bounds__(256) void k_zero(
    int* __restrict__ cnt, int* __restrict__ tok, float* __restrict__ wgt)
{
    const int i = blockIdx.x * 256 + threadIdx.x;
    if (i < NE) cnt[i] = 0;
    if (i < NE * CAP) { tok[i] = 0; wgt[i] = 0.f; }
}

// ---------------- router: rmsnorm + gate + top4 + lists ----------------
__global__ __launch_bounds__(256) void k_router(
    const float* __restrict__ x, const float* __restrict__ nscale,
    const float* __restrict__ gw, const float* __restrict__ gb,
    __bf16* __restrict__ tbf, int* __restrict__ cnt,
    int* __restrict__ tok, float* __restrict__ wgt,
    int* __restrict__ res, float* __restrict__ rw)
{
    const int t = blockIdx.x, tid = threadIdx.x;
    __shared__ float tl[HH];
    __shared__ float red[4];
    __shared__ float logits[NE];

    float4 xv = ((const float4*)(x + (size_t)t * HH))[tid];
    float ss = xv.x * xv.x + xv.y * xv.y + xv.z * xv.z + xv.w * xv.w;
    #pragma unroll
    for (int o = 32; o; o >>= 1) ss += __shfl_xor(ss, o);
    if ((tid & 63) == 0) red[tid >> 6] = ss;
    __syncthreads();
    const float mean = (red[0] + red[1] + red[2] + red[3]) * (1.0f / HH);
    const float r = rsqrtf(mean + 1e-5f);
    float4 sc = ((const float4*)nscale)[tid];
    float4 tv;
    tv.x = xv.x * r * sc.x; tv.y = xv.y * r * sc.y;
    tv.z = xv.z * r * sc.z; tv.w = xv.w * r * sc.w;

    ((float4*)tl)[tid] = tv;
    bf16x4 pv = { (__bf16)tv.x, (__bf16)tv.y, (__bf16)tv.z, (__bf16)tv.w };
    *(bf16x4*)(tbf + (size_t)t * HH + tid * 4) = pv;
    __syncthreads();

    const int e = tid >> 3, q = tid & 7;
    const float4* gr = (const float4*)(gw + e * HH + q * 128);
    const float4* tr = (const float4*)(tl + q * 128);
    float s = 0.f;
    #pragma unroll 8
    for (int j = 0; j < 32; ++j) {
        float4 g = gr[j], v = tr[j];
        s += g.x * v.x + g.y * v.y + g.z * v.z + g.w * v.w;
    }
    s += __shfl_xor(s, 1); s += __shfl_xor(s, 2); s += __shfl_xor(s, 4);
    if (q == 0) logits[e] = s + gb[e];
    __syncthreads();

    if (tid == 0) {
        float v[NK]; int id[NK]; unsigned used = 0;
        for (int k = 0; k < NK; ++k) {
            float best = -1e30f; int bi = 0;
            for (int ee = 0; ee < NE; ++ee)
                if (!((used >> ee) & 1u) && logits[ee] > best) { best = logits[ee]; bi = ee; }
            used |= 1u << bi; v[k] = best; id[k] = bi;
        }
        float ex[NK], se = 0.f;
        for (int k = 0; k < NK; ++k) { ex[k] = __expf(v[k] - v[0]); se += ex[k]; }
        const float inv = 1.0f / se;
        for (int k = 0; k < NK; ++k) {
            const float wk = ex[k] * inv;
            int pos = atomicAdd(&cnt[id[k]], 1);
            if (pos < CAP) {
                tok[id[k] * CAP + pos] = t;
                wgt[id[k] * CAP + pos] = wk;
            }
            res[t * NK + k] = (id[k] << 16) | (pos & 0xffff);
            rw[t * NK + k] = wk;
        }
    }
}

// ---------------- mlp1: h = swiglu(t @ w1[e]^T + b1) * route_w ----------------
// Linear full-K staging of 32 w1-rows (bf16, swizzled) + branch-free K-loop:
// 2 slot-groups/wave, B prefetched a full K-step ahead, ds_reads via two
// loop-invariant bases + immediate offsets. Slots >= Me compute to 0 via
// pre-zeroed tok/wgt.
__global__ __launch_bounds__(512, 4) void k_mlp1(
    const float* __restrict__ w1, const float* __restrict__ b1,
    const __bf16* __restrict__ tbf, const int* __restrict__ cnt,
    const int* __restrict__ tok, const float* __restrict__ wgt,
    __bf16* __restrict__ h)
{
    const int mtile = blockIdx.x;   // 64 tiles x 32 w1-rows
    const int e     = blockIdx.y;
    const int z     = blockIdx.z;   // slot half: 0 -> 0..127, 1 -> 128..255
    const int tid   = threadIdx.x;

    int Me = cnt[e]; Me = Me > CAP ? CAP : Me;
    if (z * 128 >= Me) return;

    __shared__ __bf16 A[MT * 1024];   // 64 KiB

    // ---- stage A: contiguous 128 KiB fp32 region, two 8-load batches ----
    const float* abase = w1 + ((size_t)e * 2048 + (size_t)mtile * MT) * HH;
    #pragma unroll
    for (int half = 0; half < 2; ++half) {
        float4 v[8];
        #pragma unroll
        for (int i = 0; i < 8; ++i)
            v[i] = ((const float4*)abase)[half * 4096 + i * 512 + tid];
        #pragma unroll
        for (int i = 0; i < 8; ++i) {
            const int fi = half * 4096 + i * 512 + tid;
            const int row = fi >> 8, c4 = fi & 255;
            bf16x4 pv = { (__bf16)v[i].x, (__bf16)v[i].y, (__bf16)v[i].z, (__bf16)v[i].w };
            *(bf16x4*)((char*)A + row * 2048 + ((c4 * 8) ^ ((row & 7) << 4))) = pv;
        }
    }

    const int lane = tid & 63, wv = tid >> 6;
    const int mr = lane & 15, qd = lane >> 4;
    const int s = wv & 1, g = wv >> 1;
    const int r16 = s * 16 + mr;
    const int aswz = (r16 & 7) << 4;
    // addr(ks) = r16*2048 + ((ks*64 + qd*16) ^ aswz)
    //          = base{E,O} + kk*128   (ks = 2kk / 2kk+1) -> pure imm offsets
    const char* baseE = (const char*)A + r16 * 2048 + ((qd * 16) ^ (aswz & 0x30)) + (aswz & 0x40);
    const char* baseO = (const char*)A + r16 * 2048 + ((qd * 16) ^ (aswz & 0x30)) + (64 - (aswz & 0x40));

    const int slot0 = (z * 8 + g * 2) * 16 + mr;
    const int slot1 = slot0 + 16;
    const int tk0 = tok[e * CAP + slot0];
    const int tk1 = tok[e * CAP + slot1];
    const __bf16* bp0 = tbf + (size_t)tk0 * HH + qd * 8;
    const __bf16* bp1 = tbf + (size_t)tk1 * HH + qd * 8;

    f32x4v acc0 = {0.f, 0.f, 0.f, 0.f};
    f32x4v acc1 = {0.f, 0.f, 0.f, 0.f};

    __syncthreads();

    bf16x8 c00 = *(const bf16x8*)(bp0);          // (ks even, slot0)
    bf16x8 c01 = *(const bf16x8*)(bp1);          // (ks even, slot1)
    bf16x8 c10 = *(const bf16x8*)(bp0 + 32);     // (ks odd,  slot0)
    bf16x8 c11 = *(const bf16x8*)(bp1 + 32);     // (ks odd,  slot1)

    #pragma unroll
    for (int kk = 0; kk < 16; ++kk) {
        bf16x8 n00, n01, n10, n11;
        if (kk < 15) {
            n00 = *(const bf16x8*)(bp0 + (2 * kk + 2) * 32);
            n01 = *(const bf16x8*)(bp1 + (2 * kk + 2) * 32);
            n10 = *(const bf16x8*)(bp0 + (2 * kk + 3) * 32);
            n11 = *(const bf16x8*)(bp1 + (2 * kk + 3) * 32);
        }
        const bf16x8 a0 = *(const bf16x8*)(baseE + kk * 128);
        acc0 = __builtin_amdgcn_mfma_f32_16x16x32_bf16(a0, c00, acc0, 0, 0, 0);
        acc1 = __builtin_amdgcn_mfma_f32_16x16x32_bf16(a0, c01, acc1, 0, 0, 0);
        const bf16x8 a1 = *(const bf16x8*)(baseO + kk * 128);
        acc0 = __builtin_amdgcn_mfma_f32_16x16x32_bf16(a1, c10, acc0, 0, 0, 0);
        acc1 = __builtin_amdgcn_mfma_f32_16x16x32_bf16(a1, c11, acc1, 0, 0, 0);
        c00 = n00; c01 = n01; c10 = n10; c11 = n11;
    }

    // ---- epilogue: bias + swiglu + route weight (wgt=0 for dead slots) ----
    const int rowb = mtile * MT + s * 16 + qd * 4;   // absolute w1-row (even)
    const float4 bv = *(const float4*)(b1 + e * 2048 + rowb);
    const float wt0 = wgt[e * CAP + slot0];
    const float wt1 = wgt[e * CAP + slot1];
    {
        float g0 = acc0[0] + bv.x, l0 = acc0[1] + bv.y;
        float g1 = acc0[2] + bv.z, l1 = acc0[3] + bv.w;
        g0 = fminf(g0, 7.f); g1 = fminf(g1, 7.f);
        l0 = fminf(fmaxf(l0, -7.f), 7.f); l1 = fminf(fmaxf(l1, -7.f), 7.f);
        const float h0 = g0 * (1.f / (1.f + __expf(-1.702f * g0))) * (l0 + 1.f) * wt0;
        const float h1 = g1 * (1.f / (1.f + __expf(-1.702f * g1))) * (l1 + 1.f) * wt0;
        bf16x2 hv = { (__bf16)h0, (__bf16)h1 };
        *(bf16x2*)(h + ((size_t)e * CAP + slot0) * FF + (rowb >> 1)) = hv;
    }
    {
        float g0 = acc1[0] + bv.x, l0 = acc1[1] + bv.y;
        float g1 = acc1[2] + bv.z, l1 = acc1[3] + bv.w;
        g0 = fminf(g0, 7.f); g1 = fminf(g1, 7.f);
        l0 = fminf(fmaxf(l0, -7.f), 7.f); l1 = fminf(fmaxf(l1, -7.f), 7.f);
        const float h0 = g0 * (1.f / (1.f + __expf(-1.702f * g0))) * (l0 + 1.f) * wt1;
        const float h1 = g1 * (1.f / (1.f + __expf(-1.702f * g1))) * (l1 + 1.f) * wt1;
        bf16x2 hv = { (__bf16)h0, (__bf16)h1 };
        *(bf16x2*)(h + ((size_t)e * CAP + slot1) * FF + (rowb >> 1)) = hv;
    }
}

// ---------------- mlp2: h2[e,slot,:] = h[e,slot,:] @ w2[e]^T ----------------
__global__ __launch_bounds__(512, 4) void k_mlp2(
    const float* __restrict__ w2, const __bf16* __restrict__ h,
    const int* __restrict__ cnt, __bf16* __restrict__ h2)
{
    const int mtile = blockIdx.x;   // 32 tiles x 32 out-cols
    const int e     = blockIdx.y;
    const int z     = blockIdx.z;
    const int tid   = threadIdx.x;

    int Me = cnt[e]; Me = Me > CAP ? CAP : Me;
    if (z * 128 >= Me) return;

    __shared__ __bf16 A[MT * 1024];   // 64 KiB

    const float* abase = w2 + ((size_t)e * HH + (size_t)mtile * MT) * FF;
    #pragma unroll
    for (int half = 0; half < 2; ++half) {
        float4 v[8];
        #pragma unroll
        for (int i = 0; i < 8; ++i)
            v[i] = ((const float4*)abase)[half * 4096 + i * 512 + tid];
        #pragma unroll
        for (int i = 0; i < 8; ++i) {
            const int fi = half * 4096 + i * 512 + tid;
            const int row = fi >> 8, c4 = fi & 255;
            bf16x4 pv = { (__bf16)v[i].x, (__bf16)v[i].y, (__bf16)v[i].z, (__bf16)v[i].w };
            *(bf16x4*)((char*)A + row * 2048 + ((c4 * 8) ^ ((row & 7) << 4))) = pv;
        }
    }

    const int lane = tid & 63, wv = tid >> 6;
    const int mr = lane & 15, qd = lane >> 4;
    const int s = wv & 1, g = wv >> 1;
    const int r16 = s * 16 + mr;
    const int aswz = (r16 & 7) << 4;
    const char* baseE = (const char*)A + r16 * 2048 + ((qd * 16) ^ (aswz & 0x30)) + (aswz & 0x40);
    const char* baseO = (const char*)A + r16 * 2048 + ((qd * 16) ^ (aswz & 0x30)) + (64 - (aswz & 0x40));

    const int slot0 = (z * 8 + g * 2) * 16 + mr;
    const int slot1 = slot0 + 16;
    const __bf16* bp0 = h + ((size_t)e * CAP + slot0) * FF + qd * 8;
    const __bf16* bp1 = h + ((size_t)e * CAP + slot1) * FF + qd * 8;

    f32x4v acc0 = {0.f, 0.f, 0.f, 0.f};
    f32x4v acc1 = {0.f, 0.f, 0.f, 0.f};

    __syncthreads();

    bf16x8 c00 = *(const bf16x8*)(bp0);
    bf16x8 c01 = *(const bf16x8*)(bp1);
    bf16x8 c10 = *(const bf16x8*)(bp0 + 32);
    bf16x8 c11 = *(const bf16x8*)(bp1 + 32);

    #pragma unroll
    for (int kk = 0; kk < 16; ++kk) {
        bf16x8 n00, n01, n10, n11;
        if (kk < 15) {
            n00 = *(const bf16x8*)(bp0 + (2 * kk + 2) * 32);
            n01 = *(const bf16x8*)(bp1 + (2 * kk + 2) * 32);
            n10 = *(const bf16x8*)(bp0 + (2 * kk + 3) * 32);
            n11 = *(const bf16x8*)(bp1 + (2 * kk + 3) * 32);
        }
        const bf16x8 a0 = *(const bf16x8*)(baseE + kk * 128);
        acc0 = __builtin_amdgcn_mfma_f32_16x16x32_bf16(a0, c00, acc0, 0, 0, 0);
        acc1 = __builtin_amdgcn_mfma_f32_16x16x32_bf16(a0, c01, acc1, 0, 0, 0);
        const bf16x8 a1 = *(const bf16x8*)(baseO + kk * 128);
        acc0 = __builtin_amdgcn_mfma_f32_16x16x32_bf16(a1, c10, acc0, 0, 0, 0);
        acc1 = __builtin_amdgcn_mfma_f32_16x16x32_bf16(a1, c11, acc1, 0, 0, 0);
        c00 = n00; c01 = n01; c10 = n10; c11 = n11;
    }

    const int rowb = mtile * MT + s * 16 + qd * 4;   // h2 column base
    {
        bf16x4 ov = { (__bf16)acc0[0], (__bf16)acc0[1], (__bf16)acc0[2], (__bf16)acc0[3] };
        *(bf16x4*)&h2[((size_t)e * CAP + slot0) * HH + rowb] = ov;
    }
    {
        bf16x4 ov = { (__bf16)acc1[0], (__bf16)acc1[1], (__bf16)acc1[2], (__bf16)acc1[3] };
        *(bf16x4*)&h2[((size_t)e * CAP + slot1) * HH + rowb] = ov;
    }
}

// ---------------- combine: out = x + sum_k (h2[e_k,pos_k,:] + w_k*b2[e_k,:]) ----------------
__global__ __launch_bounds__(256) void k_combine(
    const float* __restrict__ x, const float* __restrict__ b2,
    const __bf16* __restrict__ h2, const int* __restrict__ res,
    const float* __restrict__ rw, float* __restrict__ out)
{
    const int t = blockIdx.x, tid = threadIdx.x;
    float4 acc = ((const float4*)(x + (size_t)t * HH))[tid];
    #pragma unroll
    for (int k = 0; k < NK; ++k) {
        const int es = res[t * NK + k];
        const float wt = rw[t * NK + k];
        const int e = es >> 16, pos = es & 0xffff;
        if (pos < CAP) {
            bf16x4 hv = *(const bf16x4*)(h2 + ((size_t)e * CAP + pos) * HH + tid * 4);
            float4 bv = ((const float4*)(b2 + (size_t)e * HH))[tid];
            acc.x += (float)hv[0] + wt * bv.x;
            acc.y += (float)hv[1] + wt * bv.y;
            acc.z += (float)hv[2] + wt * bv.z;
            acc.w += (float)hv[3] + wt * bv.w;
        }
    }
    ((float4*)(out + (size_t)t * HH))[tid] = acc;
}

extern "C" void kernel_launch(void* const* d_in, const int* in_sizes, int n_in,
                              void* d_out, int out_size, void* d_ws, size_t ws_size,
                              hipStream_t stream) {
    const float* x      = (const float*)d_in[0];
    const float* nscale = (const float*)d_in[1];
    const float* gw     = (const float*)d_in[2];
    const float* gb     = (const float*)d_in[3];
    const float* w1     = (const float*)d_in[4];
    const float* b1     = (const float*)d_in[5];
    const float* w2     = (const float*)d_in[6];
    const float* b2     = (const float*)d_in[7];
    float* out = (float*)d_out;

    char* ws = (char*)d_ws;
    int*    cnt = (int*)(ws);
    int*    tok = (int*)(ws + OFF_TOK);
    float*  wgt = (float*)(ws + OFF_WGT);
    int*    res = (int*)(ws + OFF_ES);
    float*  rw  = (float*)(ws + OFF_RW);
    __bf16* tbf = (__bf16*)(ws + OFF_T);
    __bf16* h   = (__bf16*)(ws + OFF_H);
    __bf16* h2  = (__bf16*)(ws + OFF_H2);

    k_zero<<<32, 256, 0, stream>>>(cnt, tok, wgt);
    k_router<<<1024, 256, 0, stream>>>(x, nscale, gw, gb, tbf, cnt, tok, wgt, res, rw);
    k_mlp1<<<dim3(64, 32, 2), 512, 0, stream>>>(w1, b1, tbf, cnt, tok, wgt, h);
    k_mlp2<<<dim3(32, 32, 2), 512, 0, stream>>>(w2, h, cnt, h2);
    k_combine<<<1024, 256, 0, stream>>>(x, b2, h2, res, rw, out);
}